// Round 2
// baseline (178.281 us; speedup 1.0000x reference)
//
#include <hip/hip_runtime.h>
#include <hip/hip_bf16.h>

#define NTOK   8192
#define TOPK   2
#define NEXP   8
#define KDIM   1024
#define NDIM   1024
#define MOUT   (NTOK * TOPK)        // 16384 dispatched rows
#define BM     128
#define BN     128
#define BK     64
#define MAXT   (MOUT / BM + NEXP)   // 136 tile slots (expert-boundary padding)
#define NBLK   (MAXT * (NDIM / BN)) // 1088 gemm blocks
#define CLSCAP (NBLK / 8)           // 136 positions per XCD class

// ws int-offset layout:
//   [16384, 32768)      row_token (16384 ints)  -> ends at byte 128K
// ws byte layout:
//   [128KiB, +16MiB)    w_bf16 [8,1024,1024]   (x stays f32; converted in-GEMM)
#define ROWTOK   16384
#define WB_OFF   (128 * 1024)
#define WB_BYTES (NEXP * NDIM * KDIM * 2)
#define WS_NEED  ((size_t)(WB_OFF + WB_BYTES))

typedef unsigned short ushort_t;
typedef __attribute__((ext_vector_type(8))) short short8;
typedef __attribute__((ext_vector_type(4))) float floatx4;
typedef __attribute__((address_space(1))) const unsigned int gu32;
typedef __attribute__((address_space(3))) unsigned int lu32;

// ---------------------------------------------------------------------------
// Analytic block -> (row0, rows, e, cy) mapping (XCD-aware placement).
// ---------------------------------------------------------------------------
__device__ __forceinline__ void map_block(int b, const int* __restrict__ splits,
                                          int& row0, int& rows, int& e_out,
                                          int& cy) {
  int sp[8], off[8], n[8], take[8];
  int o = 0;
#pragma unroll
  for (int e = 0; e < 8; ++e) {
    sp[e] = splits[e];
    off[e] = o;
    o += sp[e];
    int tiles = (sp[e] + BM - 1) / BM;
    n[e] = 8 * tiles;
    take[e] = (n[e] < CLSCAP) ? n[e] : CLSCAP;
  }
  const int c = b & 7, i = b >> 3;
  int e = -1, j = 0;
  if (i < take[c]) {
    e = c; j = i;
  } else {
    int freeBefore = 0;
#pragma unroll
    for (int cc = 0; cc < 8; ++cc)
      if (cc < c) freeBefore += CLSCAP - take[cc];
    int spos = freeBefore + (i - take[c]);
    int acc = 0;
#pragma unroll
    for (int ee = 0; ee < 8; ++ee) {
      int sp_e = n[ee] - take[ee];
      if (e < 0 && spos < acc + sp_e) { e = ee; j = CLSCAP + (spos - acc); }
      acc += sp_e;
    }
    if (e < 0) { rows = 0; return; }   // idle position
  }
  int t = j >> 3;
  cy = j & 7;
  row0 = off[e] + t * BM;
  int rem = off[e] + sp[e] - row0;
  rows = (rem > BM) ? BM : rem;
  if (rows < 0) rows = 0;
  e_out = e;
}

// ---------------------------------------------------------------------------
// Setup: scatter invert + fp32->bf16 convert of W ONLY (48 MB traffic,
// was 96 MB). x is consumed as f32 directly by the GEMM's A staging.
// ---------------------------------------------------------------------------
__global__ __launch_bounds__(256)
void convert_w(const float* __restrict__ w, const int* __restrict__ scatter,
               ushort_t* __restrict__ wb, int* __restrict__ ws) {
  const int N8W = NEXP * NDIM * KDIM / 8;   // 1,048,576 x 32B chunks
  int gtid = blockIdx.x * 256 + threadIdx.x;

  if (gtid < MOUT) {
    int s = scatter[gtid];          // flat slot gtid -> output row s
    ws[ROWTOK + s] = gtid / TOPK;   // token of that slot
  }

  for (int i = gtid; i < N8W; i += gridDim.x * 256) {
    const float4* src = ((const float4*)w) + 2 * (size_t)i;
    float4 v0 = src[0];
    float4 v1 = src[1];
    union { __hip_bfloat162 h; unsigned int u; } p0, p1, p2, p3;
    p0.h = __float22bfloat162_rn(make_float2(v0.x, v0.y));
    p1.h = __float22bfloat162_rn(make_float2(v0.z, v0.w));
    p2.h = __float22bfloat162_rn(make_float2(v1.x, v1.y));
    p3.h = __float22bfloat162_rn(make_float2(v1.z, v1.w));
    uint4 u4; u4.x = p0.u; u4.y = p1.u; u4.z = p2.u; u4.w = p3.u;
    ((uint4*)wb)[i] = u4;
  }
}

// ---------------------------------------------------------------------------
// Grouped GEMM: B staged bf16 via global_load_lds (inverse-swizzled source);
// A staged from f32 x with in-register cvt + swizzled ds_write_b128 (the
// write-side XOR matches the read-side XOR -> conflict-free, both-sides rule).
// Round-0 pointer style / launch bounds (known-best codegen).
// ---------------------------------------------------------------------------
__global__ __launch_bounds__(256, 3)
void moe_gemm_fast(const float* __restrict__ x,     // [8192,1024] f32
                   const ushort_t* __restrict__ wbm, // [8,1024,1024] bf16
                   const int* __restrict__ splits,
                   const int* __restrict__ ws,
                   float* __restrict__ out) {
  __shared__ ushort_t As[BM * BK];   // 16 KiB, swizzled row-major [128][64]
  __shared__ ushort_t Bs[BN * BK];   // 16 KiB

  int row0, rows, e, cyi;
  map_block(blockIdx.x, splits, row0, rows, e, cyi);
  if (rows == 0) return;
  const int c0 = cyi * BN;

  const int tid  = threadIdx.x;
  const int lane = tid & 63;
  const int wave = tid >> 6;
  const int wm   = (wave >> 1) * 64;
  const int wn   = (wave & 1) * 64;
  const int quad = lane >> 4;
  const int l16  = lane & 15;

  const int* __restrict__ row_token = ws + ROWTOK;

  // Staging geometry: instr t covers 8 rows (wave*32+t*8 ..+7); lane -> row
  // +lane/8, 16B chunk lane&7.
  const int lrow8  = lane >> 3;
  const int chunk  = lane & 7;
  const int gchunk = chunk ^ lrow8;       // B: inverse-swizzled global source

  // A: f32 source pointers (natural chunk), LDS slot gets the XOR instead.
  //   row r = wave*32 + t*8 + lrow8  ->  (r&7) == lrow8 for all t,
  //   so the swizzled column slot (chunk ^ lrow8) is t-invariant.
  const float* ax[4];
#pragma unroll
  for (int t = 0; t < 4; ++t) {
    int r  = wave * 32 + t * 8 + lrow8;
    int rc = (r < rows) ? r : (rows - 1);          // clamp tail to a valid row
    ax[t] = x + (size_t)row_token[row0 + rc] * KDIM + chunk * 8;
  }
  // A LDS write address (bytes are ushort-indexed): row*BK + swizzled_col*8
  const int awofs = (wave * 32 + lrow8) * BK + ((chunk ^ lrow8) * 8);

  const ushort_t* bptr[4];
#pragma unroll
  for (int t = 0; t < 4; ++t) {
    int r = wave * 32 + t * 8 + lrow8;
    bptr[t] = wbm + ((size_t)e * NDIM + c0 + r) * KDIM + gchunk * 8;
  }

  floatx4 zero = {0.f, 0.f, 0.f, 0.f};
  floatx4 acc[4][4];
#pragma unroll
  for (int i = 0; i < 4; ++i)
#pragma unroll
    for (int j = 0; j < 4; ++j) acc[i][j] = zero;

#pragma unroll 2
  for (int kk = 0; kk < KDIM; kk += BK) {
    // B: fire async DMA first
#pragma unroll
    for (int t = 0; t < 4; ++t) {
      __builtin_amdgcn_global_load_lds(
          (gu32*)(const void*)(bptr[t] + kk),
          (lu32*)(void*)(Bs + (wave * 32 + t * 8) * BK), 16, 0, 0);
    }
    // A: f32 loads -> cvt -> swizzled LDS write
    float4 va[4][2];
#pragma unroll
    for (int t = 0; t < 4; ++t) {
      va[t][0] = *(const float4*)(ax[t] + kk);
      va[t][1] = *(const float4*)(ax[t] + kk + 4);
    }
#pragma unroll
    for (int t = 0; t < 4; ++t) {
      union { __hip_bfloat162 h; unsigned int u; } p0, p1, p2, p3;
      p0.h = __float22bfloat162_rn(make_float2(va[t][0].x, va[t][0].y));
      p1.h = __float22bfloat162_rn(make_float2(va[t][0].z, va[t][0].w));
      p2.h = __float22bfloat162_rn(make_float2(va[t][1].x, va[t][1].y));
      p3.h = __float22bfloat162_rn(make_float2(va[t][1].z, va[t][1].w));
      uint4 u4; u4.x = p0.u; u4.y = p1.u; u4.z = p2.u; u4.w = p3.u;
      *(uint4*)(&As[awofs + t * 8 * BK]) = u4;
    }
    __syncthreads();

#pragma unroll
    for (int k2 = 0; k2 < 2; ++k2) {
      short8 af[4], bf[4];
#pragma unroll
      for (int i = 0; i < 4; ++i) {
        int m = wm + i * 16 + l16;
        af[i] = *(const short8*)(&As[m * BK + (((k2 * 4 + quad) ^ (m & 7)) * 8)]);
      }
#pragma unroll
      for (int j = 0; j < 4; ++j) {
        int n = wn + j * 16 + l16;
        bf[j] = *(const short8*)(&Bs[n * BK + (((k2 * 4 + quad) ^ (n & 7)) * 8)]);
      }
#pragma unroll
      for (int i = 0; i < 4; ++i)
#pragma unroll
        for (int j = 0; j < 4; ++j)
          acc[i][j] = __builtin_amdgcn_mfma_f32_16x16x32_bf16(af[i], bf[j],
                                                              acc[i][j], 0, 0, 0);
    }
    __syncthreads();
  }

#pragma unroll
  for (int i = 0; i < 4; ++i) {
#pragma unroll
    for (int r = 0; r < 4; ++r) {
      int lrow = wm + i * 16 + quad * 4 + r;
      if (lrow < rows) {
        float* o = out + (size_t)(row0 + lrow) * NDIM + c0 + wn + l16;
#pragma unroll
        for (int j = 0; j < 4; ++j) o[j * 16] = acc[i][j][r];
      }
    }
  }
}

// ---------------------------------------------------------------------------
// Fallback path (ws too small for bf16 W staging): scatter-invert kernel +
// fused in-loop convert GEMM with the same analytic mapping.
// ---------------------------------------------------------------------------
__global__ void setup_only(const int* __restrict__ scatter,
                           int* __restrict__ ws) {
  int gtid = blockIdx.x * blockDim.x + threadIdx.x;
  if (gtid < MOUT) {
    int s = scatter[gtid];
    ws[ROWTOK + s] = gtid / TOPK;
  }
}

__global__ __launch_bounds__(256)
void moe_gemm_fallback(const float* __restrict__ x,
                       const float* __restrict__ w,
                       const int* __restrict__ splits,
                       const int* __restrict__ ws,
                       float* __restrict__ out) {
  __shared__ ushort_t As[BM * BK];
  __shared__ ushort_t Bs[BN * BK];

  int row0, rows, e, cyi;
  map_block(blockIdx.x, splits, row0, rows, e, cyi);
  if (rows == 0) return;
  const int c0 = cyi * BN;

  const int tid  = threadIdx.x;
  const int lane = tid & 63;
  const int wave = tid >> 6;
  const int wm   = (wave >> 1) * 64;
  const int wn   = (wave & 1) * 64;
  const int quad = lane >> 4;
  const int l16  = lane & 15;

  const int* __restrict__ row_token = ws + ROWTOK;

  const int f4    = tid & 15;
  const int rbase = tid >> 4;
  const int swz   = (f4 >> 1) ^ (rbase & 7);
  const int wroff = rbase * BK + swz * 8 + (f4 & 1) * 4;

  const float* __restrict__ wb = w + ((size_t)e * NDIM + c0) * KDIM;
  const float* pA[8];
#pragma unroll
  for (int i = 0; i < 8; ++i) {
    int r = rbase + i * 16;
    pA[i] = (r < rows) ? (x + (size_t)row_token[row0 + r] * KDIM + f4 * 4)
                       : nullptr;
  }
  const float* pB0 = wb + (size_t)rbase * KDIM + f4 * 4;

  floatx4 zero = {0.f, 0.f, 0.f, 0.f};
  floatx4 acc[4][4];
#pragma unroll
  for (int i = 0; i < 4; ++i)
#pragma unroll
    for (int j = 0; j < 4; ++j) acc[i][j] = zero;

#pragma unroll 1
  for (int kk = 0; kk < KDIM; kk += BK) {
#pragma unroll
    for (int i = 0; i < 8; ++i) {
      float4 v = {0.f, 0.f, 0.f, 0.f};
      if (pA[i]) v = *(const float4*)(pA[i] + kk);
      union { __hip_bfloat162 h; unsigned int u; } lo, hi;
      lo.h = __float22bfloat162_rn(make_float2(v.x, v.y));
      hi.h = __float22bfloat162_rn(make_float2(v.z, v.w));
      uint2 u2; u2.x = lo.u; u2.y = hi.u;
      *(uint2*)(&As[wroff + i * 16 * BK]) = u2;
    }
#pragma unroll
    for (int i = 0; i < 8; ++i) {
      float4 v = *(const float4*)(pB0 + (size_t)i * 16 * KDIM + kk);
      union { __hip_bfloat162 h; unsigned int u; } lo, hi;
      lo.h = __float22bfloat162_rn(make_float2(v.x, v.y));
      hi.h = __float22bfloat162_rn(make_float2(v.z, v.w));
      uint2 u2; u2.x = lo.u; u2.y = hi.u;
      *(uint2*)(&Bs[wroff + i * 16 * BK]) = u2;
    }
    __syncthreads();
#pragma unroll
    for (int k2 = 0; k2 < 2; ++k2) {
      short8 af[4], bf[4];
#pragma unroll
      for (int i = 0; i < 4; ++i) {
        int m = wm + i * 16 + l16;
        af[i] = *(const short8*)(&As[m * BK + ((k2 * 4 + quad) ^ (m & 7)) * 8]);
      }
#pragma unroll
      for (int j = 0; j < 4; ++j) {
        int n = wn + j * 16 + l16;
        bf[j] = *(const short8*)(&Bs[n * BK + ((k2 * 4 + quad) ^ (n & 7)) * 8]);
      }
#pragma unroll
      for (int i = 0; i < 4; ++i)
#pragma unroll
        for (int j = 0; j < 4; ++j)
          acc[i][j] = __builtin_amdgcn_mfma_f32_16x16x32_bf16(af[i], bf[j],
                                                              acc[i][j], 0, 0, 0);
    }
    __syncthreads();
  }

#pragma unroll
  for (int i = 0; i < 4; ++i) {
#pragma unroll
    for (int r = 0; r < 4; ++r) {
      int lrow = wm + i * 16 + quad * 4 + r;
      if (lrow < rows) {
        float* o = out + (size_t)(row0 + lrow) * NDIM + c0 + wn + l16;
#pragma unroll
        for (int j = 0; j < 4; ++j) o[j * 16] = acc[i][j][r];
      }
    }
  }
}

// ---------------------------------------------------------------------------
extern "C" void kernel_launch(void* const* d_in, const int* in_sizes, int n_in,
                              void* d_out, int out_size, void* d_ws, size_t ws_size,
                              hipStream_t stream) {
  const float* x       = (const float*)d_in[0];   // [8192,1024] f32
  const float* weights = (const float*)d_in[1];   // [8,1024,1024] f32
  const int*   scatter = (const int*)d_in[2];     // [8192,2] i32
  const int*   splits  = (const int*)d_in[3];     // [8] i32
  float*       out     = (float*)d_out;           // [16384,1024] f32
  int*         ws      = (int*)d_ws;

  if (ws_size >= WS_NEED) {
    ushort_t* wb = (ushort_t*)((char*)d_ws + WB_OFF);
    convert_w<<<dim3(2048), dim3(256), 0, stream>>>(weights, scatter, wb, ws);
    moe_gemm_fast<<<dim3(NBLK), dim3(256), 0, stream>>>(x, wb, splits, ws, out);
  } else {
    setup_only<<<dim3(MOUT / 256), dim3(256), 0, stream>>>(scatter, ws);
    moe_gemm_fallback<<<dim3(NBLK), dim3(256), 0, stream>>>(x, weights, splits,
                                                            ws, out);
  }
}

// Round 3
// 152.194 us; speedup vs baseline: 1.1714x; 1.1714x over previous
//
#include <hip/hip_runtime.h>
#include <hip/hip_bf16.h>

#define NTOK   8192
#define TOPK   2
#define NEXP   8
#define KDIM   1024
#define NDIM   1024
#define MOUT   (NTOK * TOPK)        // 16384 dispatched rows
#define BM     128
#define BN     128
#define BK     64
#define MAXT   (MOUT / BM + NEXP)   // 136 tile slots (expert-boundary padding)
#define NBLK   (MAXT * (NDIM / BN)) // 1088 gemm blocks
#define CLSCAP (NBLK / 8)           // 136 positions per XCD class

// ws int-offset layout:
//   [16384, 32768)      row_token (16384 ints)  -> ends at byte 128K
// ws byte layout:
//   [128KiB, +16MiB)    x_bf16 [8192,1024]
//   [next,  +16MiB)     w_bf16 [8,1024,1024]
#define ROWTOK   16384
#define XB_OFF   (128 * 1024)
#define XB_BYTES (NTOK * KDIM * 2)
#define WB_OFF   (XB_OFF + XB_BYTES)
#define WB_BYTES (NEXP * NDIM * KDIM * 2)
#define WS_NEED  ((size_t)(WB_OFF + WB_BYTES))

typedef unsigned short ushort_t;
typedef __attribute__((ext_vector_type(8))) short short8;
typedef __attribute__((ext_vector_type(4))) float floatx4;
typedef __attribute__((address_space(1))) const unsigned int gu32;
typedef __attribute__((address_space(3))) unsigned int lu32;

// ---------------------------------------------------------------------------
// Analytic block -> (row0, rows, e, cy) mapping (XCD-aware placement).
// Position b: class c = b%8 (round-robin XCD), in-class index i = b/8.
// Expert e's entry list L_e = its tiles x 8 cy's (tile-major). Class e takes
// min(|L_e|, CLSCAP) of L_e; remainders spill into leftover class capacity in
// class order. ~60 uniform scalar ops per block; no device table needed.
// Returns rows=0 for idle positions.
// ---------------------------------------------------------------------------
__device__ __forceinline__ void map_block(int b, const int* __restrict__ splits,
                                          int& row0, int& rows, int& e_out,
                                          int& cy) {
  int sp[8], off[8], n[8], take[8];
  int o = 0;
#pragma unroll
  for (int e = 0; e < 8; ++e) {
    sp[e] = splits[e];
    off[e] = o;
    o += sp[e];
    int tiles = (sp[e] + BM - 1) / BM;
    n[e] = 8 * tiles;
    take[e] = (n[e] < CLSCAP) ? n[e] : CLSCAP;
  }
  const int c = b & 7, i = b >> 3;
  int e = -1, j = 0;
  if (i < take[c]) {
    e = c; j = i;
  } else {
    int freeBefore = 0;
#pragma unroll
    for (int cc = 0; cc < 8; ++cc)
      if (cc < c) freeBefore += CLSCAP - take[cc];
    int spos = freeBefore + (i - take[c]);
    int acc = 0;
#pragma unroll
    for (int ee = 0; ee < 8; ++ee) {
      int sp_e = n[ee] - take[ee];
      if (e < 0 && spos < acc + sp_e) { e = ee; j = CLSCAP + (spos - acc); }
      acc += sp_e;
    }
    if (e < 0) { rows = 0; return; }   // idle position
  }
  int t = j >> 3;
  cy = j & 7;
  row0 = off[e] + t * BM;
  int rem = off[e] + sp[e] - row0;
  rows = (rem > BM) ? BM : rem;
  if (rows < 0) rows = 0;
  e_out = e;
}

// ---------------------------------------------------------------------------
// Fully-parallel setup: scatter invert + fp32->bf16 convert of x and W.
// Widened: 32B/lane reads (2x float4), 16B/lane writes (uint4).
// ---------------------------------------------------------------------------
__global__ __launch_bounds__(256)
void convert_setup(const float* __restrict__ x, const float* __restrict__ w,
                   const int* __restrict__ scatter,
                   ushort_t* __restrict__ xb, ushort_t* __restrict__ wb,
                   int* __restrict__ ws) {
  const int N8X = NTOK * KDIM / 8;                      // 1,048,576
  const int N8  = N8X + NEXP * NDIM * KDIM / 8;        // 2,097,152
  int gtid = blockIdx.x * 256 + threadIdx.x;

  if (gtid < MOUT) {
    int s = scatter[gtid];          // flat slot gtid -> output row s
    ws[ROWTOK + s] = gtid / TOPK;   // token of that slot
  }

  for (int i = gtid; i < N8; i += gridDim.x * 256) {
    const float4* src = (i < N8X) ? ((const float4*)x) + 2 * (size_t)i
                                  : ((const float4*)w) + 2 * (size_t)(i - N8X);
    float4 v0 = src[0];
    float4 v1 = src[1];
    union { __hip_bfloat162 h; unsigned int u; } p0, p1, p2, p3;
    p0.h = __float22bfloat162_rn(make_float2(v0.x, v0.y));
    p1.h = __float22bfloat162_rn(make_float2(v0.z, v0.w));
    p2.h = __float22bfloat162_rn(make_float2(v1.x, v1.y));
    p3.h = __float22bfloat162_rn(make_float2(v1.z, v1.w));
    uint4 u4; u4.x = p0.u; u4.y = p1.u; u4.z = p2.u; u4.w = p3.u;
    if (i < N8X) ((uint4*)xb)[i] = u4;
    else         ((uint4*)wb)[i - N8X] = u4;
  }
}

// ---------------------------------------------------------------------------
// Fast grouped GEMM (round-0 proven-best configuration): bf16 inputs,
// global_load_lds width-16 staging, inverse-swizzled fetch (LDS slot (r,p)
// holds global chunk p^(r&7); fragment reads use c^(m&7) -> conflict-free).
// Analytic XCD-aware block mapping. Pointer-array addressing + unroll 4 +
// __launch_bounds__(256,3): this codegen measured 47.2 us / MfmaUtil 27%.
// Known local optimum for this geometry: 3 blocks/CU (VGPR80+AGPR64),
// 2-barrier K-step; dbuf/bigger tiles lose to occupancy or makespan
// quantization (1088 tiles vs 768/512/256 slots).
// ---------------------------------------------------------------------------
__global__ __launch_bounds__(256, 3)
void moe_gemm_fast(const ushort_t* __restrict__ xb,   // [8192,1024] bf16
                   const ushort_t* __restrict__ wbm,  // [8,1024,1024] bf16
                   const int* __restrict__ splits,
                   const int* __restrict__ ws,
                   float* __restrict__ out) {
  __shared__ ushort_t As[BM * BK];   // 16 KiB, swizzled row-major [128][64]
  __shared__ ushort_t Bs[BN * BK];   // 16 KiB

  int row0, rows, e, cyi;
  map_block(blockIdx.x, splits, row0, rows, e, cyi);
  if (rows == 0) return;
  const int c0 = cyi * BN;

  const int tid  = threadIdx.x;
  const int lane = tid & 63;
  const int wave = tid >> 6;
  const int wm   = (wave >> 1) * 64;
  const int wn   = (wave & 1) * 64;
  const int quad = lane >> 4;
  const int l16  = lane & 15;

  const int* __restrict__ row_token = ws + ROWTOK;

  // Staging: instr t stages 8 rows (wave*32+t*8 ..+7); lane -> row +lane/8.
  // HW puts lane at LDS pos lane&7; we fetch global chunk (lane&7)^(row&7).
  const int lrow8  = lane >> 3;
  const int gchunk = (lane & 7) ^ lrow8;

  const ushort_t* aptr[4];
  const ushort_t* bptr[4];
#pragma unroll
  for (int t = 0; t < 4; ++t) {
    int r  = wave * 32 + t * 8 + lrow8;
    int rc = (r < rows) ? r : (rows - 1);          // clamp tail to a valid row
    aptr[t] = xb + (size_t)row_token[row0 + rc] * KDIM + gchunk * 8;
    bptr[t] = wbm + ((size_t)e * NDIM + c0 + r) * KDIM + gchunk * 8;
  }

  floatx4 zero = {0.f, 0.f, 0.f, 0.f};
  floatx4 acc[4][4];
#pragma unroll
  for (int i = 0; i < 4; ++i)
#pragma unroll
    for (int j = 0; j < 4; ++j) acc[i][j] = zero;

#pragma unroll 4
  for (int kk = 0; kk < KDIM; kk += BK) {
#pragma unroll
    for (int t = 0; t < 4; ++t) {
      __builtin_amdgcn_global_load_lds(
          (gu32*)(const void*)(aptr[t] + kk),
          (lu32*)(void*)(As + (wave * 32 + t * 8) * BK), 16, 0, 0);
      __builtin_amdgcn_global_load_lds(
          (gu32*)(const void*)(bptr[t] + kk),
          (lu32*)(void*)(Bs + (wave * 32 + t * 8) * BK), 16, 0, 0);
    }
    __syncthreads();

#pragma unroll
    for (int k2 = 0; k2 < 2; ++k2) {
      short8 af[4], bf[4];
#pragma unroll
      for (int i = 0; i < 4; ++i) {
        int m = wm + i * 16 + l16;
        af[i] = *(const short8*)(&As[m * BK + (((k2 * 4 + quad) ^ (m & 7)) * 8)]);
      }
#pragma unroll
      for (int j = 0; j < 4; ++j) {
        int n = wn + j * 16 + l16;
        bf[j] = *(const short8*)(&Bs[n * BK + (((k2 * 4 + quad) ^ (n & 7)) * 8)]);
      }
#pragma unroll
      for (int i = 0; i < 4; ++i)
#pragma unroll
        for (int j = 0; j < 4; ++j)
          acc[i][j] = __builtin_amdgcn_mfma_f32_16x16x32_bf16(af[i], bf[j],
                                                              acc[i][j], 0, 0, 0);
    }
    __syncthreads();
  }

#pragma unroll
  for (int i = 0; i < 4; ++i) {
#pragma unroll
    for (int r = 0; r < 4; ++r) {
      int lrow = wm + i * 16 + quad * 4 + r;
      if (lrow < rows) {
        float* o = out + (size_t)(row0 + lrow) * NDIM + c0 + wn + l16;
#pragma unroll
        for (int j = 0; j < 4; ++j) o[j * 16] = acc[i][j][r];
      }
    }
  }
}

// ---------------------------------------------------------------------------
// Fallback path (ws too small for bf16 staging): scatter-invert kernel +
// fused in-loop convert GEMM with the same analytic mapping.
// ---------------------------------------------------------------------------
__global__ void setup_only(const int* __restrict__ scatter,
                           int* __restrict__ ws) {
  int gtid = blockIdx.x * blockDim.x + threadIdx.x;
  if (gtid < MOUT) {
    int s = scatter[gtid];
    ws[ROWTOK + s] = gtid / TOPK;
  }
}

__global__ __launch_bounds__(256)
void moe_gemm_fallback(const float* __restrict__ x,
                       const float* __restrict__ w,
                       const int* __restrict__ splits,
                       const int* __restrict__ ws,
                       float* __restrict__ out) {
  __shared__ ushort_t As[BM * BK];
  __shared__ ushort_t Bs[BN * BK];

  int row0, rows, e, cyi;
  map_block(blockIdx.x, splits, row0, rows, e, cyi);
  if (rows == 0) return;
  const int c0 = cyi * BN;

  const int tid  = threadIdx.x;
  const int lane = tid & 63;
  const int wave = tid >> 6;
  const int wm   = (wave >> 1) * 64;
  const int wn   = (wave & 1) * 64;
  const int quad = lane >> 4;
  const int l16  = lane & 15;

  const int* __restrict__ row_token = ws + ROWTOK;

  const int f4    = tid & 15;
  const int rbase = tid >> 4;
  const int swz   = (f4 >> 1) ^ (rbase & 7);
  const int wroff = rbase * BK + swz * 8 + (f4 & 1) * 4;

  const float* __restrict__ wb = w + ((size_t)e * NDIM + c0) * KDIM;
  const float* pA[8];
#pragma unroll
  for (int i = 0; i < 8; ++i) {
    int r = rbase + i * 16;
    pA[i] = (r < rows) ? (x + (size_t)row_token[row0 + r] * KDIM + f4 * 4)
                       : nullptr;
  }
  const float* pB0 = wb + (size_t)rbase * KDIM + f4 * 4;

  floatx4 zero = {0.f, 0.f, 0.f, 0.f};
  floatx4 acc[4][4];
#pragma unroll
  for (int i = 0; i < 4; ++i)
#pragma unroll
    for (int j = 0; j < 4; ++j) acc[i][j] = zero;

#pragma unroll 1
  for (int kk = 0; kk < KDIM; kk += BK) {
#pragma unroll
    for (int i = 0; i < 8; ++i) {
      float4 v = {0.f, 0.f, 0.f, 0.f};
      if (pA[i]) v = *(const float4*)(pA[i] + kk);
      union { __hip_bfloat162 h; unsigned int u; } lo, hi;
      lo.h = __float22bfloat162_rn(make_float2(v.x, v.y));
      hi.h = __float22bfloat162_rn(make_float2(v.z, v.w));
      uint2 u2; u2.x = lo.u; u2.y = hi.u;
      *(uint2*)(&As[wroff + i * 16 * BK]) = u2;
    }
#pragma unroll
    for (int i = 0; i < 8; ++i) {
      float4 v = *(const float4*)(pB0 + (size_t)i * 16 * KDIM + kk);
      union { __hip_bfloat162 h; unsigned int u; } lo, hi;
      lo.h = __float22bfloat162_rn(make_float2(v.x, v.y));
      hi.h = __float22bfloat162_rn(make_float2(v.z, v.w));
      uint2 u2; u2.x = lo.u; u2.y = hi.u;
      *(uint2*)(&Bs[wroff + i * 16 * BK]) = u2;
    }
    __syncthreads();
#pragma unroll
    for (int k2 = 0; k2 < 2; ++k2) {
      short8 af[4], bf[4];
#pragma unroll
      for (int i = 0; i < 4; ++i) {
        int m = wm + i * 16 + l16;
        af[i] = *(const short8*)(&As[m * BK + ((k2 * 4 + quad) ^ (m & 7)) * 8]);
      }
#pragma unroll
      for (int j = 0; j < 4; ++j) {
        int n = wn + j * 16 + l16;
        bf[j] = *(const short8*)(&Bs[n * BK + ((k2 * 4 + quad) ^ (n & 7)) * 8]);
      }
#pragma unroll
      for (int i = 0; i < 4; ++i)
#pragma unroll
        for (int j = 0; j < 4; ++j)
          acc[i][j] = __builtin_amdgcn_mfma_f32_16x16x32_bf16(af[i], bf[j],
                                                              acc[i][j], 0, 0, 0);
    }
    __syncthreads();
  }

#pragma unroll
  for (int i = 0; i < 4; ++i) {
#pragma unroll
    for (int r = 0; r < 4; ++r) {
      int lrow = wm + i * 16 + quad * 4 + r;
      if (lrow < rows) {
        float* o = out + (size_t)(row0 + lrow) * NDIM + c0 + wn + l16;
#pragma unroll
        for (int j = 0; j < 4; ++j) o[j * 16] = acc[i][j][r];
      }
    }
  }
}

// ---------------------------------------------------------------------------
extern "C" void kernel_launch(void* const* d_in, const int* in_sizes, int n_in,
                              void* d_out, int out_size, void* d_ws, size_t ws_size,
                              hipStream_t stream) {
  const float* x       = (const float*)d_in[0];   // [8192,1024] f32
  const float* weights = (const float*)d_in[1];   // [8,1024,1024] f32
  const int*   scatter = (const int*)d_in[2];     // [8192,2] i32
  const int*   splits  = (const int*)d_in[3];     // [8] i32
  float*       out     = (float*)d_out;           // [16384,1024] f32
  int*         ws      = (int*)d_ws;

  if (ws_size >= WS_NEED) {
    ushort_t* xb = (ushort_t*)((char*)d_ws + XB_OFF);
    ushort_t* wb = (ushort_t*)((char*)d_ws + WB_OFF);
    convert_setup<<<dim3(2048), dim3(256), 0, stream>>>(x, weights, scatter,
                                                        xb, wb, ws);
    moe_gemm_fast<<<dim3(NBLK), dim3(256), 0, stream>>>(xb, wb, splits, ws, out);
  } else {
    setup_only<<<dim3(MOUT / 256), dim3(256), 0, stream>>>(scatter, ws);
    moe_gemm_fallback<<<dim3(NBLK), dim3(256), 0, stream>>>(x, weights, splits,
                                                            ws, out);
  }
}